// Round 17
// baseline (166.182 us; speedup 1.0000x reference)
//
#include <hip/hip_runtime.h>
#include <math.h>

#define BS 16
#define S 512
#define D 1024
#define H 16
#define DK 64
#define HALF 8

typedef __attribute__((ext_vector_type(8))) short short8v;
typedef __attribute__((ext_vector_type(4))) float f32x4;
typedef unsigned short ushort_t;

#define L2E 1.4426950408889634f
#define SC_STD (0.125f * L2E)
#define SC_PEN (-0.0125f * L2E)

__device__ __forceinline__ ushort_t f2bf(float f) {
  union { float f; unsigned u; } v; v.f = f;
  unsigned r = v.u + 0x7fffu + ((v.u >> 16) & 1u);
  return (ushort_t)(r >> 16);
}
__device__ __forceinline__ unsigned packbf(float a, float b) {
  return (unsigned)f2bf(a) | ((unsigned)f2bf(b) << 16);
}
__device__ __forceinline__ float bf2f(ushort_t u) {
  union { unsigned u; float f; } v; v.u = ((unsigned)u) << 16;
  return v.f;
}
__device__ __forceinline__ unsigned cvtpk(float lo, float hi) {
  unsigned r;
  asm("v_cvt_pk_bf16_f32 %0, %1, %2" : "=v"(r) : "v"(lo), "v"(hi));
  return r;
}

__device__ __forceinline__ void gload16(const void* g, void* l) {
  __builtin_amdgcn_global_load_lds(
      (const __attribute__((address_space(1))) unsigned int*)g,
      (__attribute__((address_space(3))) unsigned int*)l, 16, 0, 0);
}

#define WAIT_VM(n) asm volatile("s_waitcnt vmcnt(" #n ")" ::: "memory")
#define SBAR() __builtin_amdgcn_s_barrier()
#define SCHED() __builtin_amdgcn_sched_barrier(0)

// ---------------------------------------------------------------------------
// fused f32 -> bf16 convert: x (4096 blocks) then Wq/Wk/Wv/Wo (512 each).
// ---------------------------------------------------------------------------
__global__ __launch_bounds__(256) void cvt_fused(
    const float* __restrict__ x, const float* __restrict__ Wq,
    const float* __restrict__ Wk, const float* __restrict__ Wv,
    const float* __restrict__ Wo, ushort_t* __restrict__ dst) {
  const int bid = blockIdx.x;
  const float* src;
  int si;
  if (bid < 4096) {
    src = x; si = bid * 256 + threadIdx.x;
  } else {
    const int k = bid - 4096;
    const int w = k >> 9;
    src = (w == 0) ? Wq : (w == 1) ? Wk : (w == 2) ? Wv : Wo;
    si = (k & 511) * 256 + threadIdx.x;
  }
  const int di = bid * 256 + threadIdx.x;
  const float4 a = *(const float4*)(src + (size_t)si * 8);
  const float4 b = *(const float4*)(src + (size_t)si * 8 + 4);
  union { short8v v; unsigned u[4]; } t;
  t.u[0] = packbf(a.x, a.y);
  t.u[1] = packbf(a.z, a.w);
  t.u[2] = packbf(b.x, b.y);
  t.u[3] = packbf(b.z, b.w);
  *(short8v*)(dst + (size_t)di * 8) = t.v;
}

// ---------------------------------------------------------------------------
// Fused QKV GEMM + PSI EPILOGUE, 8-PHASE schedule at a REGISTER-SAFE tile:
// BM=256, BN=128, BK=64, 512 threads (8 waves 4M x 2N), per-wave 64x64 ->
// acc[4][4]=64 AGPR (~210 total regs, fits 252; R11/R12's 256^2 needed 278
// -> spilled). Triple-buffered LDS (144KB) gives depth-2 prefetch:
// stage(t+2) after the tile-top barrier, WAIT vmcnt(6) (t+1 stays in
// flight, 2 tiles of HBM cover). 4 phases/tile: {4x ds_read_b128 -> barrier
// -> setprio(1) 8xMFMA setprio(0)}, operand-half reuse order a0b0,a0b1,
// a1b1,a1b0. bn 0..7=Q, 8..15=K, 16..23=V^T. XCD-partitioned.
// ---------------------------------------------------------------------------
__global__ __launch_bounds__(512) void gemm_qkv(
    const ushort_t* __restrict__ A, const ushort_t* __restrict__ Wcat,
    const float* __restrict__ bq, const float* __restrict__ bk,
    const float* __restrict__ bv, ushort_t* __restrict__ QK,
    ushort_t* __restrict__ Vt, float4* __restrict__ QPn,
    float4* __restrict__ KPn) {
  const int id = blockIdx.x;              // 0..767
  const int xcd = id & 7, r0 = id >> 3;   // r0 0..95
  const int bn = xcd * 3 + (r0 % 3);      // 0..23 (128-col panels)
  const int bm = r0 / 3;                  // 0..31 (256-row panels)
  const int mat = bn >> 3;                // 0=Q 1=K 2=V
  const int tid = threadIdx.x;
  const int lane = tid & 63, wid = tid >> 6;  // 8 waves
  const int wm = wid >> 1, wn = wid & 1;      // 4M x 2N
  const int lq = lane & 15, g = lane >> 4;

  __shared__ __align__(16) ushort_t sA[3][256 * 64];  // 96 KB
  __shared__ __align__(16) ushort_t sB[3][128 * 64];  // 48 KB

  f32x4 acc[4][4];
#pragma unroll
  for (int i = 0; i < 4; i++)
#pragma unroll
    for (int j = 0; j < 4; j++) acc[i][j] = (f32x4){0.f, 0.f, 0.f, 0.f};

  // persistent pre-swizzled source pointers; advance 64 cols per K-tile
  const ushort_t* aSrc[4];
  const ushort_t* bSrc[2];
#pragma unroll
  for (int ld = 0; ld < 4; ++ld) {
    const int gi = ld * 512 + tid;
    const int row = gi >> 3, slot = gi & 7;
    aSrc[ld] = A + (size_t)(bm * 256 + row) * 1024 + ((slot ^ (row & 7)) * 8);
  }
#pragma unroll
  for (int ld = 0; ld < 2; ++ld) {
    const int gi = ld * 512 + tid;
    const int row = gi >> 3, slot = gi & 7;
    bSrc[ld] =
        Wcat + (size_t)(bn * 128 + row) * 1024 + ((slot ^ (row & 7)) * 8);
  }

  auto stage = [&](int k, int kt) {
#pragma unroll
    for (int ld = 0; ld < 4; ++ld)
      gload16(aSrc[ld] + kt * 64, &sA[k][(size_t)(ld * 512 + tid) * 8]);
#pragma unroll
    for (int ld = 0; ld < 2; ++ld)
      gload16(bSrc[ld] + kt * 64, &sB[k][(size_t)(ld * 512 + tid) * 8]);
  };

#define DSA(AF, IH, BI)                                                      \
  _Pragma("unroll") for (int i = 0; i < 2; ++i)                              \
  _Pragma("unroll") for (int ks = 0; ks < 2; ++ks) {                         \
    const int row_ = wm * 64 + ((IH)*2 + i) * 16 + lq;                       \
    AF[i][ks] = *(const short8v*)&sA[BI]                                     \
        [row_ * 64 + (((ks * 4 + g) ^ (row_ & 7)) * 8)];                     \
  }
#define DSB(BF, JH, BI)                                                      \
  _Pragma("unroll") for (int j = 0; j < 2; ++j)                              \
  _Pragma("unroll") for (int ks = 0; ks < 2; ++ks) {                         \
    const int row_ = wn * 64 + ((JH)*2 + j) * 16 + lq;                       \
    BF[j][ks] = *(const short8v*)&sB[BI]                                     \
        [row_ * 64 + (((ks * 4 + g) ^ (row_ & 7)) * 8)];                     \
  }
#define MM(IH, JH, AF, BF)                                                   \
  _Pragma("unroll") for (int ks = 0; ks < 2; ++ks)                           \
  _Pragma("unroll") for (int i = 0; i < 2; ++i)                              \
  _Pragma("unroll") for (int j = 0; j < 2; ++j)                              \
    acc[(IH)*2 + i][(JH)*2 + j] = __builtin_amdgcn_mfma_f32_16x16x32_bf16(   \
        AF[i][ks], BF[j][ks], acc[(IH)*2 + i][(JH)*2 + j], 0, 0, 0);

  stage(0, 0);
  stage(1, 1);

  for (int t = 0; t < 16; ++t) {
    const int bi = t % 3;
    if (t == 15) { WAIT_VM(0); } else { WAIT_VM(6); }  // tile t landed
    SBAR();
    SCHED();
    if (t + 2 < 16) stage((t + 2) % 3, t + 2);  // depth-2 prefetch
    short8v a0[2][2], a1[2][2], b0[2][2], b1[2][2];
    // P0: (a0,b0)
    DSA(a0, 0, bi);
    DSB(b0, 0, bi);
    SBAR();
    __builtin_amdgcn_s_setprio(1);
    MM(0, 0, a0, b0);
    __builtin_amdgcn_s_setprio(0);
    // P1: (a0,b1)
    DSB(b1, 1, bi);
    SBAR();
    __builtin_amdgcn_s_setprio(1);
    MM(0, 1, a0, b1);
    __builtin_amdgcn_s_setprio(0);
    // P2: (a1,b1)
    DSA(a1, 1, bi);
    SBAR();
    __builtin_amdgcn_s_setprio(1);
    MM(1, 1, a1, b1);
    __builtin_amdgcn_s_setprio(0);
    // P3: (a1,b0) -- b0 re-read (cheap)
    DSB(b0, 0, bi);
    SBAR();
    __builtin_amdgcn_s_setprio(1);
    MM(1, 0, a1, b0);
    __builtin_amdgcn_s_setprio(0);
  }

  const float* bias = (mat == 0) ? bq : (mat == 1) ? bk : bv;
  const size_t NQKV = (size_t)BS * H * S * DK;

  if (mat < 2) {
    const int headq = (bn & 7) * 2 + wn;  // head index 0..15
    const bool penq = (headq >= HALF);    // wave-uniform
    float4* Pn = (mat == 0) ? QPn : KPn;
    ushort_t* Cbase = QK + (size_t)mat * NQKV;
#pragma unroll
    for (int i = 0; i < 4; ++i) {
      const int mb = bm * 256 + wm * 64 + i * 16 + g * 4;
      float cc[4][4];  // [j][r]
#pragma unroll
      for (int j = 0; j < 4; ++j) {
        const int n = ((bn & 7) * 128) + wn * 64 + j * 16 + lq;
        const float bvv = bias[n];
#pragma unroll
        for (int r = 0; r < 4; ++r) cc[j][r] = acc[i][j][r] + bvv;
      }
      float yv[4] = {0.f, 0.f, 0.f, 0.f};
      if (penq) {
#pragma unroll
        for (int r = 0; r < 4; ++r) {
          const float last = __shfl(cc[3][r], (lane & 48) + 15, 64);
          yv[r] = 1.0f / (1.0f + __expf(-last));
        }
#pragma unroll
        for (int j = 0; j < 4; ++j)
#pragma unroll
          for (int r = 0; r < 4; ++r) cc[j][r] *= yv[r];
        if (lq == 15) {
#pragma unroll
          for (int r = 0; r < 4; ++r) cc[3][r] = yv[r];  // dk63 = y
        }
      }
      unsigned pk[4][2];
#pragma unroll
      for (int j = 0; j < 4; ++j) {
        pk[j][0] = cvtpk(cc[j][0], cc[j][1]);
        pk[j][1] = cvtpk(cc[j][2], cc[j][3]);
      }
#pragma unroll
      for (int j = 0; j < 4; ++j) {
        const int n = ((bn & 7) * 128) + wn * 64 + j * 16 + lq;
        ushort_t* base = Cbase +
                         ((((size_t)(mb >> 9) * H + (n >> 6)) * S + (mb & 511)) * DK) +
                         (n & 63);
        base[0] = (ushort_t)pk[j][0];
        base[DK] = (ushort_t)(pk[j][0] >> 16);
        base[2 * DK] = (ushort_t)pk[j][1];
        base[3 * DK] = (ushort_t)(pk[j][1] >> 16);
      }
      if (penq) {
        float sq[4] = {0.f, 0.f, 0.f, 0.f};
#pragma unroll
        for (int j = 0; j < 4; ++j)
#pragma unroll
          for (int r = 0; r < 4; ++r) {
            const unsigned h16 =
                (r & 1) ? (pk[j][r >> 1] >> 16) : (pk[j][r >> 1] & 0xffffu);
            float xr = bf2f((ushort_t)h16);
            if (j == 3 && lq == 15) xr = 0.f;  // exclude dk63 (the y slot)
            sq[r] += xr * xr;
          }
#pragma unroll
        for (int mk = 1; mk <= 8; mk <<= 1)
#pragma unroll
          for (int r = 0; r < 4; ++r) sq[r] += __shfl_xor(sq[r], mk, 64);
        if (lq == 0) {
          const int hh = headq - HALF;
#pragma unroll
          for (int r = 0; r < 4; ++r) {
            const int m = mb + r;
            const int bb = m >> 9, ss = m & 511;
            Pn[((size_t)bb * HALF + hh) * S + ss] = make_float4(
                sq[r], yv[r] * yv[r], sqrtf(1.0f - yv[r] * yv[r] + 1e-6f), 0.f);
          }
        }
      }
    }
  } else {
    // V^T epilogue
#pragma unroll
    for (int j = 0; j < 4; ++j) {
      const int n = ((bn & 7) * 128) + wn * 64 + j * 16 + lq;
      const float bvv = bias[n];
#pragma unroll
      for (int i = 0; i < 4; ++i) {
        const int mb = bm * 256 + wm * 64 + i * 16 + g * 4;
        const int bb = mb >> 9, s0 = mb & 511;
        uint2 u;
        u.x = cvtpk(acc[i][j][0] + bvv, acc[i][j][1] + bvv);
        u.y = cvtpk(acc[i][j][2] + bvv, acc[i][j][3] + bvv);
        *(uint2*)(Vt + (((size_t)bb * H + (n >> 6)) * DK + (n & 63)) * S + s0) = u;
      }
    }
  }
#undef DSA
#undef DSB
#undef MM
}

// ---------------------------------------------------------------------------
// Out-proj GEMM, 512 threads, 4M x 2N wave grid, counted pipeline (R16).
// ---------------------------------------------------------------------------
__global__ __launch_bounds__(512) void gemm_out(
    const ushort_t* __restrict__ A, const ushort_t* __restrict__ B,
    const float* __restrict__ bias, float* __restrict__ C) {
  const int id = blockIdx.x;  // 0..511
  const int bn = id & 7, bm = id >> 3;
  const int tid = threadIdx.x;
  const int lane = tid & 63, wid = tid >> 6;
  const int wr = wid >> 1, wc = wid & 1;
  const int lq = lane & 15, g = lane >> 4;

  __shared__ __align__(16) ushort_t sA[2][128 * 64];
  __shared__ __align__(16) ushort_t sB[2][128 * 64];

  f32x4 acc[2][4];
#pragma unroll
  for (int i = 0; i < 2; i++)
#pragma unroll
    for (int j = 0; j < 4; j++) acc[i][j] = (f32x4){0.f, 0.f, 0.f, 0.f};

  auto stage = [&](int buf, int k0) {
#pragma unroll
    for (int ld = 0; ld < 2; ++ld) {
      const int gi = ld * 512 + tid;
      const int row = gi >> 3, slot = gi & 7;
      const int sslot = slot ^ (row & 7);
      gload16(A + (size_t)(bm * 128 + row) * 1024 + k0 + sslot * 8,
              &sA[buf][(size_t)gi * 8]);
      gload16(B + (size_t)(bn * 128 + row) * 1024 + k0 + sslot * 8,
              &sB[buf][(size_t)gi * 8]);
    }
  };

  stage(0, 0);
  WAIT_VM(0);
  SBAR();
  for (int t = 0; t < 16; ++t) {
    if (t < 15) {
      stage((t + 1) & 1, (t + 1) * 64);
      WAIT_VM(4);
    } else {
      WAIT_VM(0);
    }
    SBAR();
    SCHED();
    const int buf = t & 1;
#pragma unroll
    for (int ks = 0; ks < 2; ++ks) {
      short8v af[2], bf[4];
#pragma unroll
      for (int i = 0; i < 2; ++i) {
        const int arow = wr * 32 + i * 16 + lq;
        af[i] = *(const short8v*)&sA[buf][arow * 64 + (((ks * 4 + g) ^ (arow & 7)) * 8)];
      }
#pragma unroll
      for (int j = 0; j < 4; ++j) {
        const int brow = wc * 64 + j * 16 + lq;
        bf[j] = *(const short8v*)&sB[buf][brow * 64 + (((ks * 4 + g) ^ (brow & 7)) * 8)];
      }
#pragma unroll
      for (int i = 0; i < 2; ++i)
#pragma unroll
        for (int j = 0; j < 4; ++j)
          acc[i][j] =
              __builtin_amdgcn_mfma_f32_16x16x32_bf16(af[i], bf[j], acc[i][j], 0, 0, 0);
    }
    SBAR();
  }

#pragma unroll
  for (int j = 0; j < 4; ++j) {
    const int n = bn * 128 + wc * 64 + j * 16 + lq;
    const float bvv = bias[n];
#pragma unroll
    for (int i = 0; i < 2; ++i) {
      const int mb = bm * 128 + wr * 32 + i * 16 + g * 4;
#pragma unroll
      for (int r = 0; r < 4; ++r)
        C[(size_t)(mb + r) * 1024 + n] = acc[i][j][r] + bvv;
    }
  }
}

// ---------------------------------------------------------------------------
// One q-tile update vs the currently staged 64-k tile. Log2-domain softmax.
// ---------------------------------------------------------------------------
template <bool MASK>
__device__ __forceinline__ void attn_tile(
    const char* sKb, const char* sVb, const float4* sPn, const short8v* qf,
    float qn, float qy2, float xqy, bool pen, float slopeL, int qg, int kt0,
    int lq, int g, f32x4* o, float& m, float& lacc) {
  float p[4][4];
  float tmax = -1e30f;
#pragma unroll
  for (int t4 = 0; t4 < 4; ++t4) {
    f32x4 acc = (f32x4){0.f, 0.f, 0.f, 0.f};
    const int row = t4 * 16 + lq;
#pragma unroll
    for (int c = 0; c < 2; ++c) {
      const short8v ka =
          *(const short8v*)(sKb + row * 128 + (((c * 4 + g) ^ (row & 7)) * 16));
      acc = __builtin_amdgcn_mfma_f32_16x16x32_bf16(ka, qf[c], acc, 0, 0, 0);
    }
#pragma unroll
    for (int r = 0; r < 4; ++r) {
      const int kg = kt0 + t4 * 16 + g * 4 + r;
      const float abL = slopeL * (float)(qg - kg);
      float s;
      if (!pen) {
        s = acc[r] * SC_STD + abL;
      } else {
        const float4 kp = sPn[t4 * 16 + g * 4 + r];
        const float kn = kp.x, ky2 = kp.y, xky = kp.z;
        const float d2 = qn + kn - 2.0f * acc[r];
        const float tt = fmaxf(d2, 0.0f) + 1e-12f;
        const float rs = rsqrtf(tt);
        const float pd = tt * rs;  // = sqrt(tt)
        const float tmp = (xqy + xky - pd) * 0.5f;
        const float lca = fmaxf(fmaxf(qy2, ky2), 1.0f - tmp * tmp);
        const float num = (d2 + ky2 - qy2) * (0.5f * rs);
        const float lout = num * num + qy2;
        const float dxy = pd - xqy;
        const bool ex = (pd <= xqy) || (dxy * dxy + ky2 <= 1.0f);
        s = (ex ? lca : lout) * SC_PEN + abL;
      }
      if (MASK && kg >= qg) s = -1e30f;
      p[t4][r] = s;
      tmax = fmaxf(tmax, s);
    }
  }
  tmax = fmaxf(tmax, __shfl_xor(tmax, 16, 64));
  tmax = fmaxf(tmax, __shfl_xor(tmax, 32, 64));
  const float mnew = fmaxf(m, tmax);
  if (__any(mnew > m)) {
    const float fsc = exp2f(m - mnew);
#pragma unroll
    for (int dt = 0; dt < 4; ++dt) o[dt] *= fsc;
    lacc *= fsc;
    m = mnew;
  }
  float ls = 0.f;
#pragma unroll
  for (int t4 = 0; t4 < 4; ++t4)
#pragma unroll
    for (int r = 0; r < 4; ++r) {
      float pv = exp2f(p[t4][r] - m);
      if (MASK && p[t4][r] < -1e29f) pv = 0.f;
      p[t4][r] = pv;
      ls += pv;
    }
  ls += __shfl_xor(ls, 16, 64);
  ls += __shfl_xor(ls, 32, 64);
  lacc += ls;

  unsigned pk0[4], pk1[4];
#pragma unroll
  for (int t4 = 0; t4 < 4; ++t4) {
    pk0[t4] = cvtpk(p[t4][0], p[t4][1]);
    pk1[t4] = cvtpk(p[t4][2], p[t4][3]);
  }
  const int s0 = lq | (((g * 2) & 3) << 4);
  const int s1 = lq | (((g * 2 + 1) & 3) << 4);
  const bool hi = (g >= 2);
#pragma unroll
  for (int c = 0; c < 2; ++c) {
    const unsigned a0 = (unsigned)__shfl((int)pk0[2 * c], s0, 64);
    const unsigned b0 = (unsigned)__shfl((int)pk0[2 * c + 1], s0, 64);
    const unsigned a1 = (unsigned)__shfl((int)pk1[2 * c], s0, 64);
    const unsigned b1 = (unsigned)__shfl((int)pk1[2 * c + 1], s0, 64);
    const unsigned a2 = (unsigned)__shfl((int)pk0[2 * c], s1, 64);
    const unsigned b2 = (unsigned)__shfl((int)pk0[2 * c + 1], s1, 64);
    const unsigned a3 = (unsigned)__shfl((int)pk1[2 * c], s1, 64);
    const unsigned b3 = (unsigned)__shfl((int)pk1[2 * c + 1], s1, 64);
    union { short8v v; unsigned u[4]; } pb;
    pb.u[0] = hi ? b0 : a0;
    pb.u[1] = hi ? b1 : a1;
    pb.u[2] = hi ? b2 : a2;
    pb.u[3] = hi ? b3 : a3;
#pragma unroll
    for (int dt = 0; dt < 4; ++dt) {
      const int vr = dt * 16 + lq;
      const short8v va =
          *(const short8v*)(sVb + vr * 128 + (((c * 4 + g) ^ (vr & 7)) * 16));
      o[dt] = __builtin_amdgcn_mfma_f32_16x16x32_bf16(va, pb.v, o[dt], 0, 0, 0);
    }
  }
}

// ---------------------------------------------------------------------------
// Flash attention with the T4 counted-vmcnt pipeline in the k-loop (R10).
// ---------------------------------------------------------------------------
__global__ __launch_bounds__(256, 4) void attn_mfma(
    const ushort_t* __restrict__ Qf, const ushort_t* __restrict__ Kf,
    const ushort_t* __restrict__ Vt, const float4* __restrict__ QPn,
    const float4* __restrict__ KPn, ushort_t* __restrict__ O) {
  const int dsp = blockIdx.x;  // 0..2047
  const int xcd = dsp & 7, idx = dsp >> 3;
  const int bh = xcd * 32 + (idx & 31);
  const int qb = 7 - (idx >> 5);  // big q-tiles dispatched first
  const int b = bh >> 4, h = bh & 15;
  const int tid = threadIdx.x, lane = tid & 63, wid = tid >> 6;
  const int lq = lane & 15, g = lane >> 4;
  const bool pen = (h >= HALF);
  const float slopeL = -exp2f(-0.5f * (float)(h + 1)) * L2E;
  const size_t hoff = ((size_t)b * H + h) * S * DK;
  const ushort_t* Vslab = Vt + hoff;  // [dk][s] bf16
  const size_t bhh = (size_t)b * HALF + (h & (HALF - 1));

  __shared__ __align__(16) char sK[2][8192];
  __shared__ __align__(16) char sV[2][8192];
  __shared__ __align__(16) float4 sPen[2][64];

  const int qg = qb * 64 + wid * 16 + lq;

  short8v qf[2];
  {
    const ushort_t* qr = Qf + hoff + (size_t)qg * DK;
    qf[0] = *(const short8v*)(qr + g * 8);
    qf[1] = *(const short8v*)(qr + 32 + g * 8);
    if (pen && g == 3) qf[1][7] = 0;  // drop y from the MFMA dot
  }
  float qn = 0, qy2 = 0, xqy = 0;
  if (pen) {
    const float4 a = QPn[bhh * S + qg];
    qn = a.x; qy2 = a.y; xqy = a.z;
  }

  const int r8 = lane >> 3;
  const int sl = ((lane & 7) ^ r8) * 8;  // pre-swizzled 16B-granule offset

  const bool extra = pen && (wid == 0);  // this wave stages sPen too
  auto stage = [&](int buf, int kt) {
#pragma unroll
    for (int i = 0; i < 2; ++i) {
      const int row = wid * 16 + i * 8 + r8;
      gload16(Kf + hoff + (size_t)(kt * 64 + row) * DK + sl,
              &sK[buf][(wid * 2 + i) * 1024]);
      gload16(Vslab + (size_t)row * S + kt * 64 + sl,
              &sV[buf][(wid * 2 + i) * 1024]);
    }
    if (extra)
      gload16(&KPn[bhh * S + kt * 64 + lane], &sPen[buf][0]);
  };

  f32x4 o[4];
#pragma unroll
  for (int dt = 0; dt < 4; ++dt) o[dt] = (f32x4){0.f, 0.f, 0.f, 0.f};
  float m = -1e30f, l = 0.f;

  stage(0, qb);
  WAIT_VM(0);
  SBAR();
  int cur = 0;
  for (int kt = qb; kt >= 0; --kt) {
    if (kt > 0) {
      stage(cur ^ 1, kt - 1);
      if (extra) { WAIT_VM(5); } else { WAIT_VM(4); }  // prev tile retired
    } else {
      WAIT_VM(0);
    }
    SBAR();
    SCHED();
    if (kt == qb)
      attn_tile<true>(sK[cur], sV[cur], sPen[cur], qf, qn, qy2, xqy, pen,
                      slopeL, qg, kt * 64, lq, g, o, m, l);
    else
      attn_tile<false>(sK[cur], sV[cur], sPen[cur], qf, qn, qy2, xqy, pen,
                       slopeL, qg, kt * 64, lq, g, o, m, l);
    SBAR();  // all waves done reading buf cur
    cur ^= 1;
  }

  const float invl = (qg == 0) ? 0.f : 1.0f / l;
  ushort_t* orow = O + ((size_t)b * S + qg) * D + h * DK;
#pragma unroll
  for (int dt = 0; dt < 4; ++dt) {
    uint2 u;
    u.x = cvtpk(o[dt][0] * invl, o[dt][1] * invl);
    u.y = cvtpk(o[dt][2] * invl, o[dt][3] * invl);
    *(uint2*)(orow + dt * 16 + g * 4) = u;
  }
}

// ---------------------------------------------------------------------------
extern "C" void kernel_launch(void* const* d_in, const int* in_sizes, int n_in,
                              void* d_out, int out_size, void* d_ws,
                              size_t ws_size, hipStream_t stream) {
  (void)in_sizes; (void)n_in; (void)out_size; (void)ws_size;
  const float* x  = (const float*)d_in[0];
  const float* Wq = (const float*)d_in[1];
  const float* bq = (const float*)d_in[2];
  const float* Wk = (const float*)d_in[3];
  const float* bk = (const float*)d_in[4];
  const float* Wv = (const float*)d_in[5];
  const float* bv = (const float*)d_in[6];
  const float* Wo = (const float*)d_in[7];
  const float* bo = (const float*)d_in[8];
  float* out = (float*)d_out;

  const size_t NQKV = (size_t)BS * H * S * DK;  // 8388608
  const size_t NW = (size_t)D * D;              // 1048576
  ushort_t* ws  = (ushort_t*)d_ws;
  ushort_t* Qb  = ws;
  ushort_t* Kbb = Qb + NQKV;
  ushort_t* Vtb = Kbb + NQKV;
  ushort_t* Ob  = Vtb + NQKV;
  ushort_t* xb  = Ob + NQKV;   // xb..Wob contiguous: cvt_fused dst is linear
  ushort_t* Wqb = xb + NQKV;
  ushort_t* Wkb = Wqb + NW;
  ushort_t* Wvb = Wkb + NW;
  ushort_t* Wob = Wvb + NW;
  float4* QPn = (float4*)(Wob + NW);
  float4* KPn = QPn + (size_t)BS * HALF * S;

  cvt_fused<<<dim3(4096 + 4 * 512), 256, 0, stream>>>(x, Wq, Wk, Wv, Wo, xb);
  gemm_qkv<<<dim3(768), 512, 0, stream>>>(xb, Wqb, bq, bk, bv, Qb, Vtb, QPn,
                                          KPn);
  attn_mfma<<<dim3(2048), 256, 0, stream>>>(Qb, Kbb, Vtb, QPn, KPn, Ob);
  gemm_out<<<dim3(512), 512, 0, stream>>>(Ob, Wob, bo, out);
}

// Round 18
// 147.202 us; speedup vs baseline: 1.1289x; 1.1289x over previous
//
#include <hip/hip_runtime.h>
#include <math.h>

#define BS 16
#define S 512
#define D 1024
#define H 16
#define DK 64
#define HALF 8

typedef __attribute__((ext_vector_type(8))) short short8v;
typedef __attribute__((ext_vector_type(4))) float f32x4;
typedef unsigned short ushort_t;

#define L2E 1.4426950408889634f
#define SC_STD (0.125f * L2E)
#define SC_PEN (-0.0125f * L2E)

__device__ __forceinline__ ushort_t f2bf(float f) {
  union { float f; unsigned u; } v; v.f = f;
  unsigned r = v.u + 0x7fffu + ((v.u >> 16) & 1u);
  return (ushort_t)(r >> 16);
}
__device__ __forceinline__ unsigned packbf(float a, float b) {
  return (unsigned)f2bf(a) | ((unsigned)f2bf(b) << 16);
}
__device__ __forceinline__ float bf2f(ushort_t u) {
  union { unsigned u; float f; } v; v.u = ((unsigned)u) << 16;
  return v.f;
}
__device__ __forceinline__ unsigned cvtpk(float lo, float hi) {
  unsigned r;
  asm("v_cvt_pk_bf16_f32 %0, %1, %2" : "=v"(r) : "v"(lo), "v"(hi));
  return r;
}

__device__ __forceinline__ void gload16(const void* g, void* l) {
  __builtin_amdgcn_global_load_lds(
      (const __attribute__((address_space(1))) unsigned int*)g,
      (__attribute__((address_space(3))) unsigned int*)l, 16, 0, 0);
}

// counted waits: previous tile's loads retired, newest N stay in flight
#define WAIT_VM(n) asm volatile("s_waitcnt vmcnt(" #n ")" ::: "memory")

// ---------------------------------------------------------------------------
// fused f32 -> bf16 convert: x (4096 blocks) then Wq/Wk/Wv/Wo (512 each).
// 75 MB of traffic at ~6 TB/s: memory-roofline (~13us).
// ---------------------------------------------------------------------------
__global__ __launch_bounds__(256) void cvt_fused(
    const float* __restrict__ x, const float* __restrict__ Wq,
    const float* __restrict__ Wk, const float* __restrict__ Wv,
    const float* __restrict__ Wo, ushort_t* __restrict__ dst) {
  const int bid = blockIdx.x;
  const float* src;
  int si;
  if (bid < 4096) {
    src = x; si = bid * 256 + threadIdx.x;
  } else {
    const int k = bid - 4096;
    const int w = k >> 9;
    src = (w == 0) ? Wq : (w == 1) ? Wk : (w == 2) ? Wv : Wo;
    si = (k & 511) * 256 + threadIdx.x;
  }
  const int di = bid * 256 + threadIdx.x;
  const float4 a = *(const float4*)(src + (size_t)si * 8);
  const float4 b = *(const float4*)(src + (size_t)si * 8 + 4);
  union { short8v v; unsigned u[4]; } t;
  t.u[0] = packbf(a.x, a.y);
  t.u[1] = packbf(a.z, a.w);
  t.u[2] = packbf(b.x, b.y);
  t.u[3] = packbf(b.z, b.w);
  *(short8v*)(dst + (size_t)di * 8) = t.v;
}

// ---------------------------------------------------------------------------
// Fused QKV GEMM + PSI EPILOGUE (R16 verified best: 73.9us). 128x128 tile,
// BK=64, 512 threads (8 waves, 4M x 2N; per-wave 32x64 -> acc[2][4] = 32
// AGPR, VGPR 52). 64KB dbuf LDS -> 2 blocks/CU, 4 waves/SIMD. T4
// counted-vmcnt pipeline: stage t+1 (4 loads/thread), WAIT vmcnt(4), raw
// barriers, no mid-loop drain. Epilogue fuses psi (sigmoid-gate + scale +
// row sum-sq) in-register. bn 0..7=Q, 8..15=K, 16..23=V^T. XCD-partitioned.
// Session scorecard for gemm structure (ref-checked each round):
//   2-barrier drain 79.5 | dbuf+drain 81.4 | counted-vmcnt 128^2 73.7 |
//   256^2 8-phase 90 (spill@252-edge) | 128x256 1blk/CU 78.8 |
//   256x128 4-phase 3buf 93.2 | THIS (counted + fused psi, 512t) 73.9.
// ---------------------------------------------------------------------------
__global__ __launch_bounds__(512) void gemm_qkv(
    const ushort_t* __restrict__ A, const ushort_t* __restrict__ Wcat,
    const float* __restrict__ bq, const float* __restrict__ bk,
    const float* __restrict__ bv, ushort_t* __restrict__ QK,
    ushort_t* __restrict__ Vt, float4* __restrict__ QPn,
    float4* __restrict__ KPn) {
  const int id = blockIdx.x;            // 0..1535
  const int xcd = id & 7, r0 = id >> 3;
  const int bn = xcd * 3 + (r0 % 3);
  const int bm = r0 / 3;
  const int tid = threadIdx.x;
  const int lane = tid & 63, wid = tid >> 6;  // 8 waves
  const int wr = wid >> 1, wc = wid & 1;      // 4M x 2N
  const int lq = lane & 15, g = lane >> 4;
  const int mat = bn >> 3;  // 0=Q 1=K 2=V

  __shared__ __align__(16) ushort_t sA[2][128 * 64];
  __shared__ __align__(16) ushort_t sB[2][128 * 64];

  f32x4 acc[2][4];
#pragma unroll
  for (int i = 0; i < 2; i++)
#pragma unroll
    for (int j = 0; j < 4; j++) acc[i][j] = (f32x4){0.f, 0.f, 0.f, 0.f};

  auto stage = [&](int buf, int k0) {
#pragma unroll
    for (int ld = 0; ld < 2; ++ld) {
      const int gi = ld * 512 + tid;
      const int row = gi >> 3, slot = gi & 7;
      const int sslot = slot ^ (row & 7);
      gload16(A + (size_t)(bm * 128 + row) * 1024 + k0 + sslot * 8,
              &sA[buf][(size_t)gi * 8]);
      gload16(Wcat + (size_t)(bn * 128 + row) * 1024 + k0 + sslot * 8,
              &sB[buf][(size_t)gi * 8]);
    }
  };

  stage(0, 0);
  WAIT_VM(0);
  __builtin_amdgcn_s_barrier();
  for (int t = 0; t < 16; ++t) {
    if (t < 15) {
      stage((t + 1) & 1, (t + 1) * 64);
      WAIT_VM(4);  // tile t's 4 loads retired; t+1 stays in flight
    } else {
      WAIT_VM(0);
    }
    __builtin_amdgcn_s_barrier();
    __builtin_amdgcn_sched_barrier(0);
    const int buf = t & 1;
#pragma unroll
    for (int ks = 0; ks < 2; ++ks) {
      short8v af[2], bf[4];
#pragma unroll
      for (int i = 0; i < 2; ++i) {
        const int arow = wr * 32 + i * 16 + lq;
        af[i] = *(const short8v*)&sA[buf][arow * 64 + (((ks * 4 + g) ^ (arow & 7)) * 8)];
      }
#pragma unroll
      for (int j = 0; j < 4; ++j) {
        const int brow = wc * 64 + j * 16 + lq;
        bf[j] = *(const short8v*)&sB[buf][brow * 64 + (((ks * 4 + g) ^ (brow & 7)) * 8)];
      }
#pragma unroll
      for (int i = 0; i < 2; ++i)
#pragma unroll
        for (int j = 0; j < 4; ++j)
          acc[i][j] =
              __builtin_amdgcn_mfma_f32_16x16x32_bf16(af[i], bf[j], acc[i][j], 0, 0, 0);
    }
    __builtin_amdgcn_s_barrier();  // all waves done reading buf -> reusable
  }

  const float* bias = (mat == 0) ? bq : (mat == 1) ? bk : bv;
  const size_t NQKV = (size_t)BS * H * S * DK;

  if (mat < 2) {
    const int headq = (bn & 7) * 2 + wc;  // head index 0..15
    const bool penq = (headq >= HALF);    // wave-uniform
    float4* Pn = (mat == 0) ? QPn : KPn;
    ushort_t* Cbase = QK + (size_t)mat * NQKV;
#pragma unroll
    for (int i = 0; i < 2; ++i) {
      const int mb = bm * 128 + wr * 32 + i * 16 + g * 4;
      float cc[4][4];  // [j][r]
#pragma unroll
      for (int j = 0; j < 4; ++j) {
        const int n = ((bn & 7) * 128) + wc * 64 + j * 16 + lq;
        const float bvv = bias[n];
#pragma unroll
        for (int r = 0; r < 4; ++r) cc[j][r] = acc[i][j][r] + bvv;
      }
      float yv[4] = {0.f, 0.f, 0.f, 0.f};
      if (penq) {
#pragma unroll
        for (int r = 0; r < 4; ++r) {
          const float last = __shfl(cc[3][r], (lane & 48) + 15, 64);
          yv[r] = 1.0f / (1.0f + __expf(-last));
        }
#pragma unroll
        for (int j = 0; j < 4; ++j)
#pragma unroll
          for (int r = 0; r < 4; ++r) cc[j][r] *= yv[r];
        if (lq == 15) {
#pragma unroll
          for (int r = 0; r < 4; ++r) cc[3][r] = yv[r];  // dk63 = y
        }
      }
      unsigned pk[4][2];
#pragma unroll
      for (int j = 0; j < 4; ++j) {
        pk[j][0] = cvtpk(cc[j][0], cc[j][1]);
        pk[j][1] = cvtpk(cc[j][2], cc[j][3]);
      }
#pragma unroll
      for (int j = 0; j < 4; ++j) {
        const int n = ((bn & 7) * 128) + wc * 64 + j * 16 + lq;
        ushort_t* base = Cbase +
                         ((((size_t)(mb >> 9) * H + (n >> 6)) * S + (mb & 511)) * DK) +
                         (n & 63);
        base[0] = (ushort_t)pk[j][0];
        base[DK] = (ushort_t)(pk[j][0] >> 16);
        base[2 * DK] = (ushort_t)pk[j][1];
        base[3 * DK] = (ushort_t)(pk[j][1] >> 16);
      }
      if (penq) {
        float sq[4] = {0.f, 0.f, 0.f, 0.f};
#pragma unroll
        for (int j = 0; j < 4; ++j)
#pragma unroll
          for (int r = 0; r < 4; ++r) {
            const unsigned h16 =
                (r & 1) ? (pk[j][r >> 1] >> 16) : (pk[j][r >> 1] & 0xffffu);
            float xr = bf2f((ushort_t)h16);
            if (j == 3 && lq == 15) xr = 0.f;  // exclude dk63 (the y slot)
            sq[r] += xr * xr;
          }
#pragma unroll
        for (int mk = 1; mk <= 8; mk <<= 1)
#pragma unroll
          for (int r = 0; r < 4; ++r) sq[r] += __shfl_xor(sq[r], mk, 64);
        if (lq == 0) {
          const int hh = headq - HALF;
#pragma unroll
          for (int r = 0; r < 4; ++r) {
            const int m = mb + r;
            const int bb = m >> 9, ss = m & 511;
            Pn[((size_t)bb * HALF + hh) * S + ss] = make_float4(
                sq[r], yv[r] * yv[r], sqrtf(1.0f - yv[r] * yv[r] + 1e-6f), 0.f);
          }
        }
      }
    }
  } else {
    // V^T epilogue
#pragma unroll
    for (int j = 0; j < 4; ++j) {
      const int n = ((bn & 7) * 128) + wc * 64 + j * 16 + lq;
      const float bvv = bias[n];
#pragma unroll
      for (int i = 0; i < 2; ++i) {
        const int mb = bm * 128 + wr * 32 + i * 16 + g * 4;
        const int bb = mb >> 9, s0 = mb & 511;
        uint2 u;
        u.x = cvtpk(acc[i][j][0] + bvv, acc[i][j][1] + bvv);
        u.y = cvtpk(acc[i][j][2] + bvv, acc[i][j][3] + bvv);
        *(uint2*)(Vt + (((size_t)bb * H + (n >> 6)) * DK + (n & 63)) * S + s0) = u;
      }
    }
  }
}

// ---------------------------------------------------------------------------
// Out-proj GEMM, 512 threads, same 4M x 2N wave grid, counted pipeline.
// ---------------------------------------------------------------------------
__global__ __launch_bounds__(512) void gemm_out(
    const ushort_t* __restrict__ A, const ushort_t* __restrict__ B,
    const float* __restrict__ bias, float* __restrict__ C) {
  const int id = blockIdx.x;  // 0..511
  const int bn = id & 7, bm = id >> 3;
  const int tid = threadIdx.x;
  const int lane = tid & 63, wid = tid >> 6;
  const int wr = wid >> 1, wc = wid & 1;
  const int lq = lane & 15, g = lane >> 4;

  __shared__ __align__(16) ushort_t sA[2][128 * 64];
  __shared__ __align__(16) ushort_t sB[2][128 * 64];

  f32x4 acc[2][4];
#pragma unroll
  for (int i = 0; i < 2; i++)
#pragma unroll
    for (int j = 0; j < 4; j++) acc[i][j] = (f32x4){0.f, 0.f, 0.f, 0.f};

  auto stage = [&](int buf, int k0) {
#pragma unroll
    for (int ld = 0; ld < 2; ++ld) {
      const int gi = ld * 512 + tid;
      const int row = gi >> 3, slot = gi & 7;
      const int sslot = slot ^ (row & 7);
      gload16(A + (size_t)(bm * 128 + row) * 1024 + k0 + sslot * 8,
              &sA[buf][(size_t)gi * 8]);
      gload16(B + (size_t)(bn * 128 + row) * 1024 + k0 + sslot * 8,
              &sB[buf][(size_t)gi * 8]);
    }
  };

  stage(0, 0);
  WAIT_VM(0);
  __builtin_amdgcn_s_barrier();
  for (int t = 0; t < 16; ++t) {
    if (t < 15) {
      stage((t + 1) & 1, (t + 1) * 64);
      WAIT_VM(4);
    } else {
      WAIT_VM(0);
    }
    __builtin_amdgcn_s_barrier();
    __builtin_amdgcn_sched_barrier(0);
    const int buf = t & 1;
#pragma unroll
    for (int ks = 0; ks < 2; ++ks) {
      short8v af[2], bf[4];
#pragma unroll
      for (int i = 0; i < 2; ++i) {
        const int arow = wr * 32 + i * 16 + lq;
        af[i] = *(const short8v*)&sA[buf][arow * 64 + (((ks * 4 + g) ^ (arow & 7)) * 8)];
      }
#pragma unroll
      for (int j = 0; j < 4; ++j) {
        const int brow = wc * 64 + j * 16 + lq;
        bf[j] = *(const short8v*)&sB[buf][brow * 64 + (((ks * 4 + g) ^ (brow & 7)) * 8)];
      }
#pragma unroll
      for (int i = 0; i < 2; ++i)
#pragma unroll
        for (int j = 0; j < 4; ++j)
          acc[i][j] =
              __builtin_amdgcn_mfma_f32_16x16x32_bf16(af[i], bf[j], acc[i][j], 0, 0, 0);
    }
    __builtin_amdgcn_s_barrier();
  }

#pragma unroll
  for (int j = 0; j < 4; ++j) {
    const int n = bn * 128 + wc * 64 + j * 16 + lq;
    const float bvv = bias[n];
#pragma unroll
    for (int i = 0; i < 2; ++i) {
      const int mb = bm * 128 + wr * 32 + i * 16 + g * 4;
#pragma unroll
      for (int r = 0; r < 4; ++r)
        C[(size_t)(mb + r) * 1024 + n] = acc[i][j][r] + bvv;
    }
  }
}

// ---------------------------------------------------------------------------
// One q-tile update vs the currently staged 64-k tile. Log2-domain softmax.
// ---------------------------------------------------------------------------
template <bool MASK>
__device__ __forceinline__ void attn_tile(
    const char* sKb, const char* sVb, const float4* sPn, const short8v* qf,
    float qn, float qy2, float xqy, bool pen, float slopeL, int qg, int kt0,
    int lq, int g, f32x4* o, float& m, float& lacc) {
  float p[4][4];
  float tmax = -1e30f;
#pragma unroll
  for (int t4 = 0; t4 < 4; ++t4) {
    f32x4 acc = (f32x4){0.f, 0.f, 0.f, 0.f};
    const int row = t4 * 16 + lq;
#pragma unroll
    for (int c = 0; c < 2; ++c) {
      const short8v ka =
          *(const short8v*)(sKb + row * 128 + (((c * 4 + g) ^ (row & 7)) * 16));
      acc = __builtin_amdgcn_mfma_f32_16x16x32_bf16(ka, qf[c], acc, 0, 0, 0);
    }
#pragma unroll
    for (int r = 0; r < 4; ++r) {
      const int kg = kt0 + t4 * 16 + g * 4 + r;
      const float abL = slopeL * (float)(qg - kg);
      float s;
      if (!pen) {
        s = acc[r] * SC_STD + abL;
      } else {
        const float4 kp = sPn[t4 * 16 + g * 4 + r];
        const float kn = kp.x, ky2 = kp.y, xky = kp.z;
        const float d2 = qn + kn - 2.0f * acc[r];
        const float tt = fmaxf(d2, 0.0f) + 1e-12f;
        const float rs = rsqrtf(tt);
        const float pd = tt * rs;  // = sqrt(tt)
        const float tmp = (xqy + xky - pd) * 0.5f;
        const float lca = fmaxf(fmaxf(qy2, ky2), 1.0f - tmp * tmp);
        const float num = (d2 + ky2 - qy2) * (0.5f * rs);
        const float lout = num * num + qy2;
        const float dxy = pd - xqy;
        const bool ex = (pd <= xqy) || (dxy * dxy + ky2 <= 1.0f);
        s = (ex ? lca : lout) * SC_PEN + abL;
      }
      if (MASK && kg >= qg) s = -1e30f;
      p[t4][r] = s;
      tmax = fmaxf(tmax, s);
    }
  }
  tmax = fmaxf(tmax, __shfl_xor(tmax, 16, 64));
  tmax = fmaxf(tmax, __shfl_xor(tmax, 32, 64));
  const float mnew = fmaxf(m, tmax);
  if (__any(mnew > m)) {
    const float fsc = exp2f(m - mnew);
#pragma unroll
    for (int dt = 0; dt < 4; ++dt) o[dt] *= fsc;
    lacc *= fsc;
    m = mnew;
  }
  float ls = 0.f;
#pragma unroll
  for (int t4 = 0; t4 < 4; ++t4)
#pragma unroll
    for (int r = 0; r < 4; ++r) {
      float pv = exp2f(p[t4][r] - m);
      if (MASK && p[t4][r] < -1e29f) pv = 0.f;
      p[t4][r] = pv;
      ls += pv;
    }
  ls += __shfl_xor(ls, 16, 64);
  ls += __shfl_xor(ls, 32, 64);
  lacc += ls;

  unsigned pk0[4], pk1[4];
#pragma unroll
  for (int t4 = 0; t4 < 4; ++t4) {
    pk0[t4] = cvtpk(p[t4][0], p[t4][1]);
    pk1[t4] = cvtpk(p[t4][2], p[t4][3]);
  }
  const int s0 = lq | (((g * 2) & 3) << 4);
  const int s1 = lq | (((g * 2 + 1) & 3) << 4);
  const bool hi = (g >= 2);
#pragma unroll
  for (int c = 0; c < 2; ++c) {
    const unsigned a0 = (unsigned)__shfl((int)pk0[2 * c], s0, 64);
    const unsigned b0 = (unsigned)__shfl((int)pk0[2 * c + 1], s0, 64);
    const unsigned a1 = (unsigned)__shfl((int)pk1[2 * c], s0, 64);
    const unsigned b1 = (unsigned)__shfl((int)pk1[2 * c + 1], s0, 64);
    const unsigned a2 = (unsigned)__shfl((int)pk0[2 * c], s1, 64);
    const unsigned b2 = (unsigned)__shfl((int)pk0[2 * c + 1], s1, 64);
    const unsigned a3 = (unsigned)__shfl((int)pk1[2 * c], s1, 64);
    const unsigned b3 = (unsigned)__shfl((int)pk1[2 * c + 1], s1, 64);
    union { short8v v; unsigned u[4]; } pb;
    pb.u[0] = hi ? b0 : a0;
    pb.u[1] = hi ? b1 : a1;
    pb.u[2] = hi ? b2 : a2;
    pb.u[3] = hi ? b3 : a3;
#pragma unroll
    for (int dt = 0; dt < 4; ++dt) {
      const int vr = dt * 16 + lq;
      const short8v va =
          *(const short8v*)(sVb + vr * 128 + (((c * 4 + g) ^ (vr & 7)) * 16));
      o[dt] = __builtin_amdgcn_mfma_f32_16x16x32_bf16(va, pb.v, o[dt], 0, 0, 0);
    }
  }
}

// ---------------------------------------------------------------------------
// Flash attention with the T4 counted-vmcnt pipeline in the k-loop (R10).
// ---------------------------------------------------------------------------
__global__ __launch_bounds__(256, 4) void attn_mfma(
    const ushort_t* __restrict__ Qf, const ushort_t* __restrict__ Kf,
    const ushort_t* __restrict__ Vt, const float4* __restrict__ QPn,
    const float4* __restrict__ KPn, ushort_t* __restrict__ O) {
  const int dsp = blockIdx.x;  // 0..2047
  const int xcd = dsp & 7, idx = dsp >> 3;
  const int bh = xcd * 32 + (idx & 31);
  const int qb = 7 - (idx >> 5);  // big q-tiles dispatched first
  const int b = bh >> 4, h = bh & 15;
  const int tid = threadIdx.x, lane = tid & 63, wid = tid >> 6;
  const int lq = lane & 15, g = lane >> 4;
  const bool pen = (h >= HALF);
  const float slopeL = -exp2f(-0.5f * (float)(h + 1)) * L2E;
  const size_t hoff = ((size_t)b * H + h) * S * DK;
  const ushort_t* Vslab = Vt + hoff;  // [dk][s] bf16
  const size_t bhh = (size_t)b * HALF + (h & (HALF - 1));

  __shared__ __align__(16) char sK[2][8192];
  __shared__ __align__(16) char sV[2][8192];
  __shared__ __align__(16) float4 sPen[2][64];

  const int qg = qb * 64 + wid * 16 + lq;

  short8v qf[2];
  {
    const ushort_t* qr = Qf + hoff + (size_t)qg * DK;
    qf[0] = *(const short8v*)(qr + g * 8);
    qf[1] = *(const short8v*)(qr + 32 + g * 8);
    if (pen && g == 3) qf[1][7] = 0;  // drop y from the MFMA dot
  }
  float qn = 0, qy2 = 0, xqy = 0;
  if (pen) {
    const float4 a = QPn[bhh * S + qg];
    qn = a.x; qy2 = a.y; xqy = a.z;
  }

  const int r8 = lane >> 3;
  const int sl = ((lane & 7) ^ r8) * 8;  // pre-swizzled 16B-granule offset

  const bool extra = pen && (wid == 0);  // this wave stages sPen too
  auto stage = [&](int buf, int kt) {
#pragma unroll
    for (int i = 0; i < 2; ++i) {
      const int row = wid * 16 + i * 8 + r8;
      gload16(Kf + hoff + (size_t)(kt * 64 + row) * DK + sl,
              &sK[buf][(wid * 2 + i) * 1024]);
      gload16(Vslab + (size_t)row * S + kt * 64 + sl,
              &sV[buf][(wid * 2 + i) * 1024]);
    }
    if (extra)
      gload16(&KPn[bhh * S + kt * 64 + lane], &sPen[buf][0]);
  };

  f32x4 o[4];
#pragma unroll
  for (int dt = 0; dt < 4; ++dt) o[dt] = (f32x4){0.f, 0.f, 0.f, 0.f};
  float m = -1e30f, l = 0.f;

  stage(0, qb);
  WAIT_VM(0);
  __builtin_amdgcn_s_barrier();
  int cur = 0;
  for (int kt = qb; kt >= 0; --kt) {
    if (kt > 0) {
      stage(cur ^ 1, kt - 1);
      if (extra) { WAIT_VM(5); } else { WAIT_VM(4); }  // prev tile retired
    } else {
      WAIT_VM(0);
    }
    __builtin_amdgcn_s_barrier();
    __builtin_amdgcn_sched_barrier(0);
    if (kt == qb)
      attn_tile<true>(sK[cur], sV[cur], sPen[cur], qf, qn, qy2, xqy, pen,
                      slopeL, qg, kt * 64, lq, g, o, m, l);
    else
      attn_tile<false>(sK[cur], sV[cur], sPen[cur], qf, qn, qy2, xqy, pen,
                       slopeL, qg, kt * 64, lq, g, o, m, l);
    __builtin_amdgcn_s_barrier();  // all waves done reading buf cur
    cur ^= 1;
  }

  const float invl = (qg == 0) ? 0.f : 1.0f / l;
  ushort_t* orow = O + ((size_t)b * S + qg) * D + h * DK;
#pragma unroll
  for (int dt = 0; dt < 4; ++dt) {
    uint2 u;
    u.x = cvtpk(o[dt][0] * invl, o[dt][1] * invl);
    u.y = cvtpk(o[dt][2] * invl, o[dt][3] * invl);
    *(uint2*)(orow + dt * 16 + g * 4) = u;
  }
}

// ---------------------------------------------------------------------------
extern "C" void kernel_launch(void* const* d_in, const int* in_sizes, int n_in,
                              void* d_out, int out_size, void* d_ws,
                              size_t ws_size, hipStream_t stream) {
  (void)in_sizes; (void)n_in; (void)out_size; (void)ws_size;
  const float* x  = (const float*)d_in[0];
  const float* Wq = (const float*)d_in[1];
  const float* bq = (const float*)d_in[2];
  const float* Wk = (const float*)d_in[3];
  const float* bk = (const float*)d_in[4];
  const float* Wv = (const float*)d_in[5];
  const float* bv = (const float*)d_in[6];
  const float* Wo = (const float*)d_in[7];
  const float* bo = (const float*)d_in[8];
  float* out = (float*)d_out;

  const size_t NQKV = (size_t)BS * H * S * DK;  // 8388608
  const size_t NW = (size_t)D * D;              // 1048576
  ushort_t* ws  = (ushort_t*)d_ws;
  ushort_t* Qb  = ws;
  ushort_t* Kbb = Qb + NQKV;
  ushort_t* Vtb = Kbb + NQKV;
  ushort_t* Ob  = Vtb + NQKV;
  ushort_t* xb  = Ob + NQKV;   // xb..Wob contiguous: cvt_fused dst is linear
  ushort_t* Wqb = xb + NQKV;
  ushort_t* Wkb = Wqb + NW;
  ushort_t* Wvb = Wkb + NW;
  ushort_t* Wob = Wvb + NW;
  float4* QPn = (float4*)(Wob + NW);
  float4* KPn = QPn + (size_t)BS * HALF * S;

  cvt_fused<<<dim3(4096 + 4 * 512), 256, 0, stream>>>(x, Wq, Wk, Wv, Wo, xb);
  gemm_qkv<<<dim3(1536), 512, 0, stream>>>(xb, Wqb, bq, bk, bv, Qb, Vtb, QPn,
                                           KPn);
  attn_mfma<<<dim3(2048), 256, 0, stream>>>(Qb, Kbb, Vtb, QPn, KPn, Ob);
  gemm_out<<<dim3(512), 512, 0, stream>>>(Ob, Wob, bo, out);
}